// Round 1
// baseline (375.292 us; speedup 1.0000x reference)
//
#include <hip/hip_runtime.h>

#define LOG2E 1.4426950408889634f

__device__ __forceinline__ float fast_sig(float x) {
  // 1/(1+exp(-x)) = rcp(1 + exp2(-x*log2e))
  return __builtin_amdgcn_rcpf(1.0f + __builtin_amdgcn_exp2f(-x * LOG2E));
}
__device__ __forceinline__ float fast_tanh(float x) {
  // tanh(x) = 1 - 2/(exp(2x)+1)
  float e = __builtin_amdgcn_exp2f(x * (2.0f * LOG2E));
  return 1.0f - 2.0f * __builtin_amdgcn_rcpf(e + 1.0f);
}

__device__ __forceinline__ float swz(float v, int pat);  // (not used; macros inline)

__global__ __launch_bounds__(256) void lstm_ae_kernel(
    const float* __restrict__ x,
    const float* __restrict__ eWih, const float* __restrict__ eWhh,
    const float* __restrict__ eBih, const float* __restrict__ eBhh,
    const float* __restrict__ dWih, const float* __restrict__ dWhh,
    const float* __restrict__ dBih, const float* __restrict__ dBhh,
    float* __restrict__ out, int B)
{
  __shared__ __align__(16) float xsh[8 * 256];
  const int tid  = threadIdx.x;
  const int grp  = tid >> 5;
  const int lane = tid & 31;
  const int b    = blockIdx.x * 8 + grp;

  // ---- stage 8 x-rows (8*256 floats) into LDS, coalesced float4 ----
  {
    const int baseF = blockIdx.x * 8 * 256;           // float index base
    const float4* src = (const float4*)(x + baseF);
    float4* dst = (float4*)xsh;
    #pragma unroll
    for (int v = 0; v < 2; ++v) {
      int idx = tid + v * 256;                         // float4 index
      if (baseF + idx * 4 < B * 256) dst[idx] = src[idx];
    }
  }
  __syncthreads();
  if (b >= B) return;

  // ---- load encoder weights: this lane owns hidden unit `lane` ----
  float whh[4][32];
  float wih[4], bb[4];
  #pragma unroll
  for (int g = 0; g < 4; ++g) {
    const int row = g * 32 + lane;
    wih[g] = eWih[row];
    bb[g]  = eBih[row] + eBhh[row];
    const float4* rp = (const float4*)(eWhh + row * 32);
    #pragma unroll
    for (int q = 0; q < 8; ++q) {
      float4 v = rp[q];
      whh[g][q*4+0] = v.x; whh[g][q*4+1] = v.y;
      whh[g][q*4+2] = v.z; whh[g][q*4+3] = v.w;
    }
  }

  // ---- encoder recurrence ----
  float h = 0.0f, c = 0.0f;
  const float* xr = &xsh[grp * 256];
  for (int t = 0; t < 256; ++t) {
    float xt = xr[t];
    float a0 = fmaf(wih[0], xt, bb[0]);
    float a1 = fmaf(wih[1], xt, bb[1]);
    float a2 = fmaf(wih[2], xt, bb[2]);
    float a3 = fmaf(wih[3], xt, bb[3]);
    int hb = __float_as_int(h);
    // broadcast h_k from lane k within the 32-lane group (ds_swizzle, or_mask=k)
    #define KS(k) { float hk = __int_as_float(__builtin_amdgcn_ds_swizzle(hb, (k) << 5)); \
      a0 = fmaf(whh[0][k], hk, a0); a1 = fmaf(whh[1][k], hk, a1);                          \
      a2 = fmaf(whh[2][k], hk, a2); a3 = fmaf(whh[3][k], hk, a3); }
    KS(0)  KS(1)  KS(2)  KS(3)  KS(4)  KS(5)  KS(6)  KS(7)
    KS(8)  KS(9)  KS(10) KS(11) KS(12) KS(13) KS(14) KS(15)
    KS(16) KS(17) KS(18) KS(19) KS(20) KS(21) KS(22) KS(23)
    KS(24) KS(25) KS(26) KS(27) KS(28) KS(29) KS(30) KS(31)
    #undef KS
    float ig = fast_sig(a0);
    float fg = fast_sig(a1);
    float gg = fast_tanh(a2);
    float og = fast_sig(a3);
    c = fmaf(fg, c, ig * gg);
    h = og * fast_tanh(c);
  }

  // ---- decoder x-gates: xg[g] = sum_i dWih[g][i]*h_i + db[g]  (32-lane reduce) ----
  float p0 = dWih[0 * 32 + lane] * h;
  float p1 = dWih[1 * 32 + lane] * h;
  float p2 = dWih[2 * 32 + lane] * h;
  float p3 = dWih[3 * 32 + lane] * h;
  #define RD(m) {                                                                           \
    p0 += __int_as_float(__builtin_amdgcn_ds_swizzle(__float_as_int(p0), ((m)<<10)|0x1F)); \
    p1 += __int_as_float(__builtin_amdgcn_ds_swizzle(__float_as_int(p1), ((m)<<10)|0x1F)); \
    p2 += __int_as_float(__builtin_amdgcn_ds_swizzle(__float_as_int(p2), ((m)<<10)|0x1F)); \
    p3 += __int_as_float(__builtin_amdgcn_ds_swizzle(__float_as_int(p3), ((m)<<10)|0x1F)); }
  RD(1) RD(2) RD(4) RD(8) RD(16)
  #undef RD
  const float xg0 = p0 + dBih[0] + dBhh[0];
  const float xg1 = p1 + dBih[1] + dBhh[1];
  const float xg2 = p2 + dBih[2] + dBhh[2];
  const float xg3 = p3 + dBih[3] + dBhh[3];
  const float w0 = dWhh[0], w1 = dWhh[1], w2 = dWhh[2], w3 = dWhh[3];

  // ---- decoder recurrence (redundant across the 32 lanes; coalesced stores) ----
  float hd = 0.0f, cd = 0.0f;
  float* op = out + (size_t)b * 256;
  for (int j = 0; j < 8; ++j) {
    float ob = 0.0f;
    #pragma unroll
    for (int l = 0; l < 32; ++l) {
      float g0 = fmaf(w0, hd, xg0);
      float g1 = fmaf(w1, hd, xg1);
      float g2 = fmaf(w2, hd, xg2);
      float g3 = fmaf(w3, hd, xg3);
      float ii = fast_sig(g0);
      float ff = fast_sig(g1);
      float gg = fast_tanh(g2);
      float oo = fast_sig(g3);
      cd = fmaf(ff, cd, ii * gg);
      hd = oo * fast_tanh(cd);
      ob = (lane == l) ? hd : ob;
    }
    op[j * 32 + lane] = ob;
  }
}

extern "C" void kernel_launch(void* const* d_in, const int* in_sizes, int n_in,
                              void* d_out, int out_size, void* d_ws, size_t ws_size,
                              hipStream_t stream) {
  const float* x    = (const float*)d_in[0];
  const float* eWih = (const float*)d_in[1];
  const float* eWhh = (const float*)d_in[2];
  const float* eBih = (const float*)d_in[3];
  const float* eBhh = (const float*)d_in[4];
  const float* dWih = (const float*)d_in[5];
  const float* dWhh = (const float*)d_in[6];
  const float* dBih = (const float*)d_in[7];
  const float* dBhh = (const float*)d_in[8];
  float* out = (float*)d_out;

  const int B = out_size / 256;          // T = 256, output [B, T, 1]
  const int grid = (B + 7) / 8;          // 8 elements per 256-thread block
  lstm_ae_kernel<<<grid, 256, 0, stream>>>(x, eWih, eWhh, eBih, eBhh,
                                           dWih, dWhh, dBih, dBhh, out, B);
}

// Round 3
// 362.088 us; speedup vs baseline: 1.0365x; 1.0365x over previous
//
#include <hip/hip_runtime.h>

#define LOG2E 1.4426950408889634f

__device__ __forceinline__ float fast_sig(float x) {
  // 1/(1+exp(-x)) = rcp(1 + exp2(-x*log2e))
  return __builtin_amdgcn_rcpf(1.0f + __builtin_amdgcn_exp2f(-x * LOG2E));
}
__device__ __forceinline__ float fast_tanh(float x) {
  // tanh(x) = 1 - 2/(exp(2x)+1)
  float e = __builtin_amdgcn_exp2f(x * (2.0f * LOG2E));
  return 1.0f - 2.0f * __builtin_amdgcn_rcpf(e + 1.0f);
}

// One LSTM time-step for hidden unit `lane` of a 32-lane group.
// ds_swizzle offset must be a literal constant -> explicit KS expansion.
__device__ __forceinline__ void enc_step(float xt, float& h, float& c,
                                         const float wih[4], const float bb[4],
                                         const float whh[4][32]) {
  float a0 = fmaf(wih[0], xt, bb[0]);
  float a1 = fmaf(wih[1], xt, bb[1]);
  float a2 = fmaf(wih[2], xt, bb[2]);
  float a3 = fmaf(wih[3], xt, bb[3]);
  int hb = __float_as_int(h);
  #define KS(k) { float hk = __int_as_float(__builtin_amdgcn_ds_swizzle(hb, (k) << 5)); \
    a0 = fmaf(whh[0][k], hk, a0); a1 = fmaf(whh[1][k], hk, a1);                          \
    a2 = fmaf(whh[2][k], hk, a2); a3 = fmaf(whh[3][k], hk, a3); }
  KS(0)  KS(1)  KS(2)  KS(3)  KS(4)  KS(5)  KS(6)  KS(7)
  KS(8)  KS(9)  KS(10) KS(11) KS(12) KS(13) KS(14) KS(15)
  KS(16) KS(17) KS(18) KS(19) KS(20) KS(21) KS(22) KS(23)
  KS(24) KS(25) KS(26) KS(27) KS(28) KS(29) KS(30) KS(31)
  #undef KS
  float ig = fast_sig(a0);
  float fg = fast_sig(a1);
  float gg = fast_tanh(a2);
  float og = fast_sig(a3);
  c = fmaf(fg, c, ig * gg);
  h = og * fast_tanh(c);
}

__global__ __launch_bounds__(256, 1) void lstm_ae_kernel(
    const float* __restrict__ x,
    const float* __restrict__ eWih, const float* __restrict__ eWhh,
    const float* __restrict__ eBih, const float* __restrict__ eBhh,
    const float* __restrict__ dWih, const float* __restrict__ dWhh,
    const float* __restrict__ dBih, const float* __restrict__ dBhh,
    float* __restrict__ out, int B)
{
  __shared__ __align__(16) float xsh[8 * 256];
  const int tid  = threadIdx.x;
  const int grp  = tid >> 5;
  const int lane = tid & 31;
  const int b    = blockIdx.x * 8 + grp;

  // ---- stage 8 x-rows (8*256 floats) into LDS, coalesced float4 ----
  {
    const int baseF = blockIdx.x * 8 * 256;           // float index base
    const float4* src = (const float4*)(x + baseF);
    float4* dst = (float4*)xsh;
    #pragma unroll
    for (int v = 0; v < 2; ++v) {
      int idx = tid + v * 256;                         // float4 index
      if (baseF + idx * 4 < B * 256) dst[idx] = src[idx];
    }
  }
  __syncthreads();
  if (b >= B) return;

  // ---- load encoder weights: this lane owns hidden unit `lane` ----
  // whh[4][32] = 128 floats/lane. MUST stay register-resident: opacity
  // barrier below stops the compiler rematerializing these loads in-loop
  // (round-1 pathology: VGPR_Count=84 -> per-step reloads, 3x instr count).
  float whh[4][32];
  float wih[4], bb[4];
  #pragma unroll
  for (int g = 0; g < 4; ++g) {
    const int row = g * 32 + lane;
    wih[g] = eWih[row];
    bb[g]  = eBih[row] + eBhh[row];
    const float4* rp = (const float4*)(eWhh + row * 32);
    #pragma unroll
    for (int q = 0; q < 8; ++q) {
      float4 v = rp[q];
      whh[g][q*4+0] = v.x; whh[g][q*4+1] = v.y;
      whh[g][q*4+2] = v.z; whh[g][q*4+3] = v.w;
    }
  }
  #pragma unroll
  for (int g = 0; g < 4; ++g) {
    asm volatile("" : "+v"(wih[g]), "+v"(bb[g]));
    #pragma unroll
    for (int k = 0; k < 32; ++k) {
      asm volatile("" : "+v"(whh[g][k]));
    }
  }

  // ---- encoder recurrence ----
  float h = 0.0f, c = 0.0f;
  const float4* xr4 = (const float4*)(&xsh[grp * 256]);
  for (int t4 = 0; t4 < 64; ++t4) {
    float4 xv = xr4[t4];
    enc_step(xv.x, h, c, wih, bb, whh);
    enc_step(xv.y, h, c, wih, bb, whh);
    enc_step(xv.z, h, c, wih, bb, whh);
    enc_step(xv.w, h, c, wih, bb, whh);
  }

  // ---- decoder x-gates: xg[g] = sum_i dWih[g][i]*h_i + db[g]  (32-lane reduce) ----
  float p0 = dWih[0 * 32 + lane] * h;
  float p1 = dWih[1 * 32 + lane] * h;
  float p2 = dWih[2 * 32 + lane] * h;
  float p3 = dWih[3 * 32 + lane] * h;
  #define RD(m) {                                                                           \
    p0 += __int_as_float(__builtin_amdgcn_ds_swizzle(__float_as_int(p0), ((m)<<10)|0x1F)); \
    p1 += __int_as_float(__builtin_amdgcn_ds_swizzle(__float_as_int(p1), ((m)<<10)|0x1F)); \
    p2 += __int_as_float(__builtin_amdgcn_ds_swizzle(__float_as_int(p2), ((m)<<10)|0x1F)); \
    p3 += __int_as_float(__builtin_amdgcn_ds_swizzle(__float_as_int(p3), ((m)<<10)|0x1F)); }
  RD(1) RD(2) RD(4) RD(8) RD(16)
  #undef RD
  const float xg0 = p0 + dBih[0] + dBhh[0];
  const float xg1 = p1 + dBih[1] + dBhh[1];
  const float xg2 = p2 + dBih[2] + dBhh[2];
  const float xg3 = p3 + dBih[3] + dBhh[3];
  const float w0 = dWhh[0], w1 = dWhh[1], w2 = dWhh[2], w3 = dWhh[3];

  // ---- decoder recurrence (redundant across the 32 lanes; coalesced stores) ----
  float hd = 0.0f, cd = 0.0f;
  float* op = out + (size_t)b * 256;
  for (int j = 0; j < 8; ++j) {
    float ob = 0.0f;
    #pragma unroll
    for (int l = 0; l < 32; ++l) {
      float g0 = fmaf(w0, hd, xg0);
      float g1 = fmaf(w1, hd, xg1);
      float g2 = fmaf(w2, hd, xg2);
      float g3 = fmaf(w3, hd, xg3);
      float ii = fast_sig(g0);
      float ff = fast_sig(g1);
      float gg = fast_tanh(g2);
      float oo = fast_sig(g3);
      cd = fmaf(ff, cd, ii * gg);
      hd = oo * fast_tanh(cd);
      ob = (lane == l) ? hd : ob;
    }
    op[j * 32 + lane] = ob;
  }
}

extern "C" void kernel_launch(void* const* d_in, const int* in_sizes, int n_in,
                              void* d_out, int out_size, void* d_ws, size_t ws_size,
                              hipStream_t stream) {
  const float* x    = (const float*)d_in[0];
  const float* eWih = (const float*)d_in[1];
  const float* eWhh = (const float*)d_in[2];
  const float* eBih = (const float*)d_in[3];
  const float* eBhh = (const float*)d_in[4];
  const float* dWih = (const float*)d_in[5];
  const float* dWhh = (const float*)d_in[6];
  const float* dBih = (const float*)d_in[7];
  const float* dBhh = (const float*)d_in[8];
  float* out = (float*)d_out;

  const int B = out_size / 256;          // T = 256, output [B, T, 1]
  const int grid = (B + 7) / 8;          // 8 elements per 256-thread block
  lstm_ae_kernel<<<grid, 256, 0, stream>>>(x, eWih, eWhh, eBih, eBhh,
                                           dWih, dWhh, dBih, dBhh, out, B);
}